// Round 1
// baseline (224.064 us; speedup 1.0000x reference)
//
#include <hip/hip_runtime.h>

#define LOG2PI_F 1.8378770664093453f

// ---- workspace layout (float offsets); total ~5.3 MB ----
#define W_ENC_PRE 0        // 512x64
#define W_INF_PRE 32768    // 512x64
#define W_BN      65536    // scale[128] then shift[128]
#define W_LATENT  65792    // 512x256
#define W_RR      196864   // 512x256  sqrt(1/(2var))
#define W_PP      327936   // 512x256  mu*rr
#define W_CC      459008   // 512x256  13.9-0.5log2pi-logsig
#define W_ENT     590080   // 128
#define W_KL      590208   // 128
#define W_A       590336   // 512x64 [j][c]
#define W_B       623104   // 512x64 [j][c]
#define W_AT      655872   // 64x512 [c][j]
#define W_BT      688640   // 64x512 [c][j]
#define W_ALPHA   721408   // 512x64 [s][c]
#define W_BETA    754176   // 512x64 [s][c]
#define W_MI      786944   // 512x512 [p][j]
#define W_DIS     1049088  // 512x512 [p][j]
#define W_MM      1311232  // 256x4 minmax partials
#define W_SUM     1312256  // 256x2 sum partials

// ---------------------------------------------------------------------------
// K1: pre-BN activations for encoder (obs[:, -128:] @ eW1) and inference
// ((hidden|obs) @ iW1). Biases dropped: BN subtracts the column mean, so any
// per-column constant cancels exactly.
__global__ __launch_bounds__(256) void k_pre(
    const float* __restrict__ obs, const float* __restrict__ hid,
    const float* __restrict__ eW1, const float* __restrict__ iW1,
    float* __restrict__ enc_pre, float* __restrict__ inf_pre) {
  __shared__ float x[16][720];  // 16 rows of inf_in = [hidden(64) | obs(656)]
  const int t = threadIdx.x;
  const int i0 = blockIdx.x * 16;
  for (int r = 0; r < 16; ++r) {
    const int i = i0 + r;
    for (int k = t; k < 720; k += 256)
      x[r][k] = (k < 64) ? hid[i * 64 + k] : obs[i * 656 + (k - 64)];
  }
  __syncthreads();
  const int c = t & 63, rg = t >> 6;  // wave-uniform rg -> LDS broadcasts
  float ai[4] = {0.f, 0.f, 0.f, 0.f}, ae[4] = {0.f, 0.f, 0.f, 0.f};
  for (int k = 0; k < 720; ++k) {
    const float w = iW1[k * 64 + c];
#pragma unroll
    for (int r = 0; r < 4; ++r) ai[r] = fmaf(x[rg * 4 + r][k], w, ai[r]);
  }
  for (int k = 0; k < 128; ++k) {  // emb_in = obs cols 528..655 -> x[592+k]
    const float w = eW1[k * 64 + c];
#pragma unroll
    for (int r = 0; r < 4; ++r) ae[r] = fmaf(x[rg * 4 + r][592 + k], w, ae[r]);
  }
#pragma unroll
  for (int r = 0; r < 4; ++r) {
    const int i = i0 + rg * 4 + r;
    inf_pre[i * 64 + c] = ai[r];
    enc_pre[i * 64 + c] = ae[r];
  }
}

// ---------------------------------------------------------------------------
// K2: per-column BN stats over the 512 agents; fold g,b into scale/shift.
__global__ __launch_bounds__(64) void k_bnstats(
    const float* __restrict__ enc_pre, const float* __restrict__ inf_pre,
    const float* __restrict__ eg, const float* __restrict__ ebt,
    const float* __restrict__ ig, const float* __restrict__ ibt,
    float* __restrict__ bn) {
  const int b = blockIdx.x, l = threadIdx.x;
  const float* src = (b < 64) ? enc_pre : inf_pre;
  const int c = b & 63;
  float v[8];
  float s = 0.f;
#pragma unroll
  for (int r = 0; r < 8; ++r) {
    v[r] = src[(l * 8 + r) * 64 + c];
    s += v[r];
  }
  for (int off = 32; off; off >>= 1) s += __shfl_down(s, off);
  const float mean = __shfl(s, 0) * (1.0f / 512.0f);
  float q = 0.f;
#pragma unroll
  for (int r = 0; r < 8; ++r) {
    const float d = v[r] - mean;
    q = fmaf(d, d, q);
  }
  for (int off = 32; off; off >>= 1) q += __shfl_down(q, off);
  if (l == 0) {
    const float var = q * (1.0f / 512.0f);
    const float g = (b < 64) ? eg[c] : ig[c];
    const float bt = (b < 64) ? ebt[c] : ibt[c];
    const float scale = g * rsqrtf(var + 1e-5f);
    bn[b] = scale;
    bn[128 + b] = bt - mean * scale;
  }
}

// ---------------------------------------------------------------------------
// K3: h = lrelu(bn(pre)); lat = h@eW2+eb2 / li = hi@iW2+ib2; produce latent,
// mi-precomputes (rr, pp, cc), and per-block entropy/kl partial sums.
__global__ __launch_bounds__(256) void k_lat(
    const float* __restrict__ enc_pre, const float* __restrict__ inf_pre,
    const float* __restrict__ bn, const float* __restrict__ eW2,
    const float* __restrict__ eb2, const float* __restrict__ iW2,
    const float* __restrict__ ib2, const float* __restrict__ eps,
    float* __restrict__ latent, float* __restrict__ rr, float* __restrict__ pp,
    float* __restrict__ cc, float* __restrict__ ent_part,
    float* __restrict__ kl_part) {
  __shared__ float h[4][64], hq[4][64];
  __shared__ float red[256];
  const int i0 = blockIdx.x * 4;
  const int t = threadIdx.x;
  {
    const int r = t >> 6, c = t & 63;
    const float ve = fmaf(enc_pre[(i0 + r) * 64 + c], bn[c], bn[128 + c]);
    h[r][c] = (ve >= 0.f) ? ve : 0.01f * ve;
    const float vi = fmaf(inf_pre[(i0 + r) * 64 + c], bn[64 + c], bn[192 + c]);
    hq[r][c] = (vi >= 0.f) ? vi : 0.01f * vi;
  }
  __syncthreads();
  float me[4] = {0.f, 0.f, 0.f, 0.f}, ve_[4] = {0.f, 0.f, 0.f, 0.f};
  float mq[4] = {0.f, 0.f, 0.f, 0.f}, vq[4] = {0.f, 0.f, 0.f, 0.f};
  for (int c = 0; c < 64; ++c) {
    const float we1 = eW2[c * 512 + t], we2 = eW2[c * 512 + t + 256];
    const float wi1 = iW2[c * 512 + t], wi2 = iW2[c * 512 + t + 256];
#pragma unroll
    for (int r = 0; r < 4; ++r) {
      const float he = h[r][c], hv = hq[r][c];
      me[r] = fmaf(he, we1, me[r]);
      ve_[r] = fmaf(he, we2, ve_[r]);
      mq[r] = fmaf(hv, wi1, mq[r]);
      vq[r] = fmaf(hv, wi2, vq[r]);
    }
  }
  const float ebm = eb2[t], ebv = eb2[t + 256];
  const float ibm = ib2[t], ibv = ib2[t + 256];
  float ent_l = 0.f, kl_l = 0.f;
#pragma unroll
  for (int r = 0; r < 4; ++r) {
    const int i = i0 + r;
    const float m = me[r] + ebm;
    const float var = fmaxf(expf(ve_[r] + ebv), 0.002f);
    const float lse = 0.5f * logf(var);
    const float sig = sqrtf(var);
    const float i2v = 0.5f / var;
    const float mqq = mq[r] + ibm;
    const float varq = fmaxf(expf(vq[r] + ibv), 0.002f);
    const float lsq = 0.5f * logf(varq);
    latent[i * 256 + t] = fmaf(sig, eps[i * 256 + t], m);
    const float r_ = sqrtf(i2v);
    rr[i * 256 + t] = r_;
    pp[i * 256 + t] = m * r_;
    cc[i * 256 + t] = 13.9f - 0.5f * LOG2PI_F - lse;
    ent_l += 0.5f + 0.5f * LOG2PI_F + lse;
    const float dmu = m - mqq;
    kl_l += lsq - lse + (var + dmu * dmu) * (0.5f / varq) - 0.5f;
  }
  red[t] = ent_l;
  __syncthreads();
  for (int o = 128; o; o >>= 1) {
    if (t < o) red[t] += red[t + o];
    __syncthreads();
  }
  if (t == 0) ent_part[blockIdx.x] = red[0];
  __syncthreads();
  red[t] = kl_l;
  __syncthreads();
  for (int o = 128; o; o >>= 1) {
    if (t < o) red[t] += red[t + o];
    __syncthreads();
  }
  if (t == 0) kl_part[blockIdx.x] = red[0];
}

// ---------------------------------------------------------------------------
// K4: A = latent @ dW1[:256], B = latent @ dW1[256:], in both [j][c] and
// [c][j] layouts. (db1 dropped: cancels in BN.)
__global__ __launch_bounds__(256) void k_AB(
    const float* __restrict__ latent, const float* __restrict__ dW1,
    float* __restrict__ A, float* __restrict__ B, float* __restrict__ At,
    float* __restrict__ Bt) {
  __shared__ float ls[16][256];
  const int j0 = blockIdx.x * 16;
  const int t = threadIdx.x;
  for (int r = 0; r < 16; ++r) ls[r][t] = latent[(j0 + r) * 256 + t];
  __syncthreads();
  const int c = t & 63, rg = t >> 6;
  float aA[4] = {0.f, 0.f, 0.f, 0.f}, aB[4] = {0.f, 0.f, 0.f, 0.f};
  for (int k = 0; k < 256; ++k) {
    const float wA = dW1[k * 64 + c];
    const float wB = dW1[(256 + k) * 64 + c];
#pragma unroll
    for (int r = 0; r < 4; ++r) {
      const float xv = ls[rg * 4 + r][k];
      aA[r] = fmaf(xv, wA, aA[r]);
      aB[r] = fmaf(xv, wB, aB[r]);
    }
  }
#pragma unroll
  for (int r = 0; r < 4; ++r) {
    const int j = j0 + rg * 4 + r;
    A[j * 64 + c] = aA[r];
    B[j * 64 + c] = aB[r];
    At[c * 512 + j] = aA[r];
    Bt[c * 512 + j] = aB[r];
  }
}

// ---------------------------------------------------------------------------
// K5: per-(s,c) BN of the pairwise net via circular correlation; emit affine
// alpha/beta so h1n = lrelu(fma(A[j]+B[p], alpha[s,c], beta[s,c])).
__global__ __launch_bounds__(256) void k_cross(
    const float* __restrict__ At, const float* __restrict__ Bt,
    const float* __restrict__ dg, const float* __restrict__ dbt,
    float* __restrict__ alpha, float* __restrict__ beta) {
  __shared__ float a[512], b[512];
  __shared__ float red[256];
  const int c = blockIdx.x, t = threadIdx.x;
  const float a0 = At[c * 512 + t], a1 = At[c * 512 + 256 + t];
  const float b0 = Bt[c * 512 + t], b1 = Bt[c * 512 + 256 + t];
  a[t] = a0;
  a[t + 256] = a1;
  b[t] = b0;
  b[t + 256] = b1;
  red[t] = a0 + a1 + b0 + b1;  // SA+SB partial
  __syncthreads();
  for (int o = 128; o; o >>= 1) {
    if (t < o) red[t] += red[t + o];
    __syncthreads();
  }
  const float S = red[0];
  __syncthreads();
  red[t] = a0 * a0 + a1 * a1 + b0 * b0 + b1 * b1;  // QA+QB partial
  __syncthreads();
  for (int o = 128; o; o >>= 1) {
    if (t < o) red[t] += red[t + o];
    __syncthreads();
  }
  const float Q = red[0];
  const float mean = S * (1.0f / 512.0f);
  const float gc = dg[c], bc = dbt[c];
  for (int sv = t; sv < 512; sv += 256) {
    float cr = 0.f;
    for (int j = 0; j < 512; ++j) cr = fmaf(a[j], b[(j - sv - 1) & 511], cr);
    const float var = (Q + 2.f * cr) * (1.0f / 512.0f) - mean * mean;
    const float al = rsqrtf(var + 1e-5f) * gc;
    alpha[sv * 64 + c] = al;
    beta[sv * 64 + c] = bc - mean * al;
  }
}

// ---------------------------------------------------------------------------
// K6: mi[p][j] over (j,p) tiles (8 x 32). s is implicit.
__global__ __launch_bounds__(256) void k_mi(
    const float* __restrict__ latent, const float* __restrict__ rr,
    const float* __restrict__ pp, const float* __restrict__ cc,
    float* __restrict__ mi) {
  __shared__ float rrs[8][256];   // 2 distinct j-rows per wave -> 2-way free
  __shared__ float pps[8][256];
  __shared__ float ccs[8][256];
  __shared__ float lats[32][257];  // +1 pad: 32 distinct p-rows conflict-free
  __shared__ float mt[32][8];
  const int t = threadIdx.x;
  const int jt = blockIdx.x & 63, pt = blockIdx.x >> 6;
  const int j0 = jt * 8, p0 = pt * 32;
  for (int idx = t; idx < 8 * 256; idx += 256) {
    const int r = idx >> 8, k = idx & 255;
    rrs[r][k] = rr[(j0 + r) * 256 + k];
    pps[r][k] = pp[(j0 + r) * 256 + k];
    ccs[r][k] = cc[(j0 + r) * 256 + k];
  }
  for (int idx = t; idx < 32 * 256; idx += 256) {
    const int r = idx >> 8, k = idx & 255;
    lats[r][k] = latent[(p0 + r) * 256 + k];
  }
  __syncthreads();
  const int jl = t >> 5, pl = t & 31;
  float acc = 0.f;
  for (int k = 0; k < 256; ++k) {
    const float v = fmaf(lats[pl][k], rrs[jl][k], -pps[jl][k]);
    const float term = fmaf(-v, v, ccs[jl][k]);
    acc += fmaxf(term, -13.9f);
  }
  mt[pl][jl] = acc * (1.0f / 256.0f);
  __syncthreads();
  {
    const int r = t >> 3, cj = t & 7;
    mi[(p0 + r) * 512 + (j0 + cj)] = mt[r][cj];
  }
}

// ---------------------------------------------------------------------------
// K7: dis[p][j], same (j,p) tiling; alpha/beta fetched over the s-band.
__global__ __launch_bounds__(256) void k_dis(
    const float* __restrict__ A, const float* __restrict__ B,
    const float* __restrict__ alpha, const float* __restrict__ beta,
    const float* __restrict__ dW2, const float* __restrict__ db2,
    float* __restrict__ dis) {
  __shared__ float As[8][64];
  __shared__ float Bs[32][65];
  __shared__ float als[39][65];
  __shared__ float bes[39][65];
  __shared__ float w2s[64];
  __shared__ float dt[32][8];
  const int t = threadIdx.x;
  const int jt = blockIdx.x & 63, pt = blockIdx.x >> 6;
  const int j0 = jt * 8, p0 = pt * 32;
  for (int idx = t; idx < 8 * 64; idx += 256)
    As[idx >> 6][idx & 63] = A[(j0 + (idx >> 6)) * 64 + (idx & 63)];
  for (int idx = t; idx < 32 * 64; idx += 256)
    Bs[idx >> 6][idx & 63] = B[(p0 + (idx >> 6)) * 64 + (idx & 63)];
  for (int idx = t; idx < 39 * 64; idx += 256) {
    const int r = idx >> 6, c = idx & 63;
    const int sr = (j0 - p0 - 32 + r) & 511;  // s for band row r
    als[r][c] = alpha[sr * 64 + c];
    bes[r][c] = beta[sr * 64 + c];
  }
  if (t < 64) w2s[t] = dW2[t];
  const float db2v = db2[0];
  __syncthreads();
  const int jl = t >> 5, pl = t & 31;
  const int rb = jl - pl + 31;  // s = j-p-1 => band row jl-pl+31
  float acc = 0.f;
  for (int c = 0; c < 64; ++c) {
    const float xv = As[jl][c] + Bs[pl][c];
    float v = fmaf(xv, als[rb][c], bes[rb][c]);
    v = (v >= 0.f) ? v : 0.01f * v;
    acc = fmaf(v, w2s[c], acc);
  }
  dt[pl][jl] = fabsf(acc + db2v);
  __syncthreads();
  {
    const int r = t >> 3, cj = t & 7;
    dis[(p0 + r) * 512 + (j0 + cj)] = dt[r][cj];
  }
}

// ---------------------------------------------------------------------------
// K8: global min/max partials of mi and dis.
__global__ __launch_bounds__(256) void k_minmax(const float* __restrict__ mi,
                                                const float* __restrict__ dis,
                                                float* __restrict__ mm) {
  __shared__ float4 red[256];
  const int t = threadIdx.x;
  float mi_mn = 3.4e38f, mi_mx = -3.4e38f, d_mn = 3.4e38f, d_mx = -3.4e38f;
  for (int i = blockIdx.x * 256 + t; i < 512 * 512; i += 65536) {
    const float m = mi[i];
    mi_mn = fminf(mi_mn, m);
    mi_mx = fmaxf(mi_mx, m);
    const float d = dis[i];
    d_mn = fminf(d_mn, d);
    d_mx = fmaxf(d_mx, d);
  }
  red[t] = make_float4(mi_mn, mi_mx, d_mn, d_mx);
  __syncthreads();
  for (int o = 128; o; o >>= 1) {
    if (t < o) {
      const float4 x = red[t], y = red[t + o];
      red[t] = make_float4(fminf(x.x, y.x), fmaxf(x.y, y.y), fminf(x.z, y.z),
                           fmaxf(x.w, y.w));
    }
    __syncthreads();
  }
  if (t == 0) {
    const float4 q = red[0];
    mm[blockIdx.x * 4 + 0] = q.x;
    mm[blockIdx.x * 4 + 1] = q.y;
    mm[blockIdx.x * 4 + 2] = q.z;
    mm[blockIdx.x * 4 + 3] = q.w;
  }
}

// ---------------------------------------------------------------------------
// K9: each block redundantly reduces the minmax partials, then sums
// min(mi_n+dis_n,1) and dis_n over its stripe.
__global__ __launch_bounds__(256) void k_sum(const float* __restrict__ mi,
                                             const float* __restrict__ dis,
                                             const float* __restrict__ mm,
                                             float* __restrict__ sp) {
  __shared__ float4 red[256];
  const int t = threadIdx.x;
  red[t] = make_float4(mm[t * 4 + 0], mm[t * 4 + 1], mm[t * 4 + 2], mm[t * 4 + 3]);
  __syncthreads();
  for (int o = 128; o; o >>= 1) {
    if (t < o) {
      const float4 x = red[t], y = red[t + o];
      red[t] = make_float4(fminf(x.x, y.x), fmaxf(x.y, y.y), fminf(x.z, y.z),
                           fmaxf(x.w, y.w));
    }
    __syncthreads();
  }
  const float4 g = red[0];
  __syncthreads();
  const float inv_mi = 1.0f / (g.y - g.x + 1e-12f);
  const float inv_d = 1.0f / (g.w - g.z + 1e-12f);
  float s1 = 0.f, s2 = 0.f;
  for (int i = blockIdx.x * 256 + t; i < 512 * 512; i += 65536) {
    const float mn_ = (mi[i] - g.x) * inv_mi;
    const float dn_ = (dis[i] - g.z) * inv_d;
    s1 += fminf(mn_ + dn_, 1.0f);
    s2 += dn_;
  }
  red[t] = make_float4(s1, s2, 0.f, 0.f);
  __syncthreads();
  for (int o = 128; o; o >>= 1) {
    if (t < o) {
      red[t].x += red[t + o].x;
      red[t].y += red[t + o].y;
    }
    __syncthreads();
  }
  if (t == 0) {
    sp[blockIdx.x * 2 + 0] = red[0].x;
    sp[blockIdx.x * 2 + 1] = red[0].y;
  }
}

// ---------------------------------------------------------------------------
// K10: final combine -> (loss, c_dis_loss, ce_loss).
__global__ __launch_bounds__(256) void k_final(const float* __restrict__ sp,
                                               const float* __restrict__ ent_part,
                                               const float* __restrict__ kl_part,
                                               float* __restrict__ out) {
  __shared__ double red[256];
  const int t = threadIdx.x;
  double S1, S2, E, K;
  red[t] = (double)sp[2 * t];
  __syncthreads();
  for (int o = 128; o; o >>= 1) {
    if (t < o) red[t] += red[t + o];
    __syncthreads();
  }
  S1 = red[0];
  __syncthreads();
  red[t] = (double)sp[2 * t + 1];
  __syncthreads();
  for (int o = 128; o; o >>= 1) {
    if (t < o) red[t] += red[t + o];
    __syncthreads();
  }
  S2 = red[0];
  __syncthreads();
  red[t] = (t < 128) ? (double)ent_part[t] : 0.0;
  __syncthreads();
  for (int o = 128; o; o >>= 1) {
    if (t < o) red[t] += red[t + o];
    __syncthreads();
  }
  E = red[0];
  __syncthreads();
  red[t] = (t < 128) ? (double)kl_part[t] : 0.0;
  __syncthreads();
  for (int o = 128; o; o >>= 1) {
    if (t < o) red[t] += red[t + o];
    __syncthreads();
  }
  K = red[0];
  if (t == 0) {
    const double entropy = E / 512.0;
    const double kl = K / 512.0;
    double l0 = entropy * 1e-4 + kl * 1e-4;
    if (l0 > 2000.0) l0 = 2000.0;
    const double ce = log1p(exp(l0));
    const double dis_loss = -S1 / 512.0;
    const double dis_norm = S2 / 512.0;
    const double c_dis = (dis_norm + dis_loss) / 512.0;
    out[0] = (float)(ce + c_dis);
    out[1] = (float)c_dis;
    out[2] = (float)ce;
  }
}

// ---------------------------------------------------------------------------
extern "C" void kernel_launch(void* const* d_in, const int* in_sizes, int n_in,
                              void* d_out, int out_size, void* d_ws,
                              size_t ws_size, hipStream_t stream) {
  (void)in_sizes;
  (void)n_in;
  (void)out_size;
  (void)ws_size;
  const float* obs = (const float*)d_in[0];
  const float* hid = (const float*)d_in[1];
  const float* eps = (const float*)d_in[2];
  const float* eW1 = (const float*)d_in[3];
  // d_in[4] eb1: cancels in BN
  const float* eg = (const float*)d_in[5];
  const float* ebt = (const float*)d_in[6];
  const float* eW2 = (const float*)d_in[7];
  const float* eb2 = (const float*)d_in[8];
  const float* iW1 = (const float*)d_in[9];
  // d_in[10] ib1: cancels in BN
  const float* ig = (const float*)d_in[11];
  const float* ibt = (const float*)d_in[12];
  const float* iW2 = (const float*)d_in[13];
  const float* ib2 = (const float*)d_in[14];
  const float* dW1 = (const float*)d_in[15];
  // d_in[16] db1: cancels in BN
  const float* dg = (const float*)d_in[17];
  const float* dbt = (const float*)d_in[18];
  const float* dW2 = (const float*)d_in[19];
  const float* db2 = (const float*)d_in[20];
  float* ws = (float*)d_ws;
  float* out = (float*)d_out;

  k_pre<<<32, 256, 0, stream>>>(obs, hid, eW1, iW1, ws + W_ENC_PRE, ws + W_INF_PRE);
  k_bnstats<<<128, 64, 0, stream>>>(ws + W_ENC_PRE, ws + W_INF_PRE, eg, ebt, ig,
                                    ibt, ws + W_BN);
  k_lat<<<128, 256, 0, stream>>>(ws + W_ENC_PRE, ws + W_INF_PRE, ws + W_BN, eW2,
                                 eb2, iW2, ib2, eps, ws + W_LATENT, ws + W_RR,
                                 ws + W_PP, ws + W_CC, ws + W_ENT, ws + W_KL);
  k_AB<<<32, 256, 0, stream>>>(ws + W_LATENT, dW1, ws + W_A, ws + W_B,
                               ws + W_AT, ws + W_BT);
  k_cross<<<64, 256, 0, stream>>>(ws + W_AT, ws + W_BT, dg, dbt, ws + W_ALPHA,
                                  ws + W_BETA);
  k_mi<<<1024, 256, 0, stream>>>(ws + W_LATENT, ws + W_RR, ws + W_PP, ws + W_CC,
                                 ws + W_MI);
  k_dis<<<1024, 256, 0, stream>>>(ws + W_A, ws + W_B, ws + W_ALPHA, ws + W_BETA,
                                  dW2, db2, ws + W_DIS);
  k_minmax<<<256, 256, 0, stream>>>(ws + W_MI, ws + W_DIS, ws + W_MM);
  k_sum<<<256, 256, 0, stream>>>(ws + W_MI, ws + W_DIS, ws + W_MM, ws + W_SUM);
  k_final<<<1, 256, 0, stream>>>(ws + W_SUM, ws + W_ENT, ws + W_KL, out);
}